// Round 4
// baseline (232.147 us; speedup 1.0000x reference)
//
#include <hip/hip_runtime.h>
#include <math.h>

#define ENC_BLOCKS 160
#define DEC_BLOCKS 800
#define BLOCK 256

#define HALF_LOG_2PI 0.91893853320467274178f

// ---------------------------------------------------------------------------
// Kernel 1: encoder. Per row of O: MLP 2->8(relu)->32(relu), accumulate the
// 32-dim activation sum. Last encoder layer (32->128, linear) is folded into
// kernel 2 since mean() commutes with a linear layer.
// Writes 32 partial sums per block to ws.
// ---------------------------------------------------------------------------
__global__ __launch_bounds__(BLOCK) void enc_kernel(
    const float* __restrict__ O, int n_ctx,
    const float* __restrict__ W0, const float* __restrict__ b0,
    const float* __restrict__ W1, const float* __restrict__ b1,
    float* __restrict__ partials)
{
    float acc[32];
#pragma unroll
    for (int k = 0; k < 32; ++k) acc[k] = 0.f;

    int tid = blockIdx.x * BLOCK + threadIdx.x;
    int stride = gridDim.x * BLOCK;
    for (int row = tid; row < n_ctx; row += stride) {
        float2 o = ((const float2*)O)[row];
        float a1[32];
#pragma unroll
        for (int k = 0; k < 32; ++k) a1[k] = b1[k];
        // fused 2->8(relu) feeding 8->32 accumulation: a0[j] live range = 1 iter
#pragma unroll
        for (int j = 0; j < 8; ++j) {
            float a0j = fmaxf(fmaf(o.x, W0[j], fmaf(o.y, W0[8 + j], b0[j])), 0.f);
#pragma unroll
            for (int k = 0; k < 32; ++k) a1[k] = fmaf(a0j, W1[j * 32 + k], a1[k]);
        }
#pragma unroll
        for (int k = 0; k < 32; ++k) acc[k] += fmaxf(a1[k], 0.f);
    }

    // wave butterfly reduce each of the 32 accumulators
#pragma unroll
    for (int k = 0; k < 32; ++k) {
        float v = acc[k];
#pragma unroll
        for (int m = 32; m >= 1; m >>= 1) v += __shfl_xor(v, m, 64);
        acc[k] = v;
    }
    __shared__ float red[BLOCK / 64][32];
    int lane = threadIdx.x & 63;
    int wv = threadIdx.x >> 6;
    if (lane == 0) {
#pragma unroll
        for (int k = 0; k < 32; ++k) red[wv][k] = acc[k];
    }
    __syncthreads();
    if (threadIdx.x < 32) {
        float s = 0.f;
#pragma unroll
        for (int w = 0; w < BLOCK / 64; ++w) s += red[w][threadIdx.x];
        partials[blockIdx.x * 32 + threadIdx.x] = s;
    }
}

// ---------------------------------------------------------------------------
// Kernel 2 (single block, 128 threads):
//   a2mean = (sum of encoder partials)/n_ctx            (32)
//   r      = a2mean @ h_W2 + h_b2                       (128)
//   rW0    = r @ g_W0[:128,:] + g_b0  -> ws             (64)
// ---------------------------------------------------------------------------
__global__ __launch_bounds__(128) void mid_kernel(
    const float* __restrict__ partials, int n_ctx,
    const float* __restrict__ hW2, const float* __restrict__ hb2,
    const float* __restrict__ gW0, const float* __restrict__ gb0,
    float* __restrict__ rW0out)
{
    __shared__ float a2m[32];
    __shared__ float rl[128];
    int t = threadIdx.x;
    if (t < 32) {
        float s = 0.f;
        for (int b = 0; b < ENC_BLOCKS; ++b) s += partials[b * 32 + t];
        a2m[t] = s / (float)n_ctx;
    }
    __syncthreads();
    {
        float s = hb2[t];
#pragma unroll
        for (int j = 0; j < 32; ++j) s = fmaf(a2m[j], hW2[j * 128 + t], s);
        rl[t] = s;
    }
    __syncthreads();
    if (t < 64) {
        float s = gb0[t];
#pragma unroll
        for (int i = 0; i < 128; ++i) s = fmaf(rl[i], gW0[i * 64 + t], s);
        rW0out[t] = s;
    }
}

// ---------------------------------------------------------------------------
// Kernel 3: decoder. One row per thread (grid-stride). Layer 0 collapses to
// relu(rW0 + x*g_W0[128,:]) and is FUSED into the 64->32 accumulation so the
// 64-wide activation never materializes (VGPR pressure: ~32 live accums).
// Then 32->16->8->2. Writes phi (float2) and accumulates the Gaussian
// log-prob; one partial per block to ws. Weight reads are wave-uniform ->
// scalar loads.
// ---------------------------------------------------------------------------
__global__ __launch_bounds__(BLOCK) void dec_kernel(
    const float* __restrict__ T, int n_tgt,
    const float* __restrict__ rW0, const float* __restrict__ gW0last,
    const float* __restrict__ W1, const float* __restrict__ b1,
    const float* __restrict__ W2, const float* __restrict__ b2,
    const float* __restrict__ W3, const float* __restrict__ b3,
    const float* __restrict__ W4, const float* __restrict__ b4,
    float* __restrict__ phi, float* __restrict__ lp_partials)
{
    float lp_acc = 0.f;
    int tid = blockIdx.x * BLOCK + threadIdx.x;
    int stride = gridDim.x * BLOCK;
    for (int row = tid; row < n_tgt; row += stride) {
        float2 t2 = ((const float2*)T)[row];
        float x = t2.x, y = t2.y;

        float a1[32];
#pragma unroll
        for (int k = 0; k < 32; ++k) a1[k] = b1[k];
        // fused layer0: a0j = relu(rW0[j] + x*gW0last[j]), consumed immediately
#pragma unroll
        for (int j = 0; j < 64; ++j) {
            float a0j = fmaxf(fmaf(x, gW0last[j], rW0[j]), 0.f);
#pragma unroll
            for (int k = 0; k < 32; ++k) a1[k] = fmaf(a0j, W1[j * 32 + k], a1[k]);
        }
#pragma unroll
        for (int k = 0; k < 32; ++k) a1[k] = fmaxf(a1[k], 0.f);

        float a2[16];
#pragma unroll
        for (int k = 0; k < 16; ++k) a2[k] = b2[k];
#pragma unroll
        for (int j = 0; j < 32; ++j) {
            float aj = a1[j];
#pragma unroll
            for (int k = 0; k < 16; ++k) a2[k] = fmaf(aj, W2[j * 16 + k], a2[k]);
        }
#pragma unroll
        for (int k = 0; k < 16; ++k) a2[k] = fmaxf(a2[k], 0.f);

        float a3[8];
#pragma unroll
        for (int k = 0; k < 8; ++k) a3[k] = b3[k];
#pragma unroll
        for (int j = 0; j < 16; ++j) {
            float aj = a2[j];
#pragma unroll
            for (int k = 0; k < 8; ++k) a3[k] = fmaf(aj, W3[j * 8 + k], a3[k]);
        }
#pragma unroll
        for (int k = 0; k < 8; ++k) a3[k] = fmaxf(a3[k], 0.f);

        float p0 = b4[0], p1 = b4[1];
#pragma unroll
        for (int j = 0; j < 8; ++j) {
            p0 = fmaf(a3[j], W4[j * 2 + 0], p0);
            p1 = fmaf(a3[j], W4[j * 2 + 1], p1);
        }
        ((float2*)phi)[row] = make_float2(p0, p1);

        // stable softplus: max(x,0) + log1p(exp(-|x|))  (matches jax.nn.softplus)
        float sp = fmaxf(p1, 0.f) + log1pf(expf(-fabsf(p1)));
        float z = (y - p0) / sp;
        lp_acc += fmaf(-0.5f * z, z, -logf(sp)) - HALF_LOG_2PI;
    }

    // block reduce lp_acc
#pragma unroll
    for (int m = 32; m >= 1; m >>= 1) lp_acc += __shfl_xor(lp_acc, m, 64);
    __shared__ float red[BLOCK / 64];
    int lane = threadIdx.x & 63;
    int wv = threadIdx.x >> 6;
    if (lane == 0) red[wv] = lp_acc;
    __syncthreads();
    if (threadIdx.x == 0) {
        float s = 0.f;
#pragma unroll
        for (int w = 0; w < BLOCK / 64; ++w) s += red[w];
        lp_partials[blockIdx.x] = s;
    }
}

// ---------------------------------------------------------------------------
// Kernel 4: reduce per-block logp partials -> mean -> last element of d_out
// ---------------------------------------------------------------------------
__global__ __launch_bounds__(256) void fin_kernel(
    const float* __restrict__ lp_partials, int nparts, int n_tgt,
    float* __restrict__ out)
{
    __shared__ float red[256];
    float s = 0.f;
    for (int i = threadIdx.x; i < nparts; i += 256) s += lp_partials[i];
    red[threadIdx.x] = s;
    __syncthreads();
    for (int o = 128; o > 0; o >>= 1) {
        if (threadIdx.x < o) red[threadIdx.x] += red[threadIdx.x + o];
        __syncthreads();
    }
    if (threadIdx.x == 0) out[0] = red[0] / (float)n_tgt;
}

extern "C" void kernel_launch(void* const* d_in, const int* in_sizes, int n_in,
                              void* d_out, int out_size, void* d_ws, size_t ws_size,
                              hipStream_t stream)
{
    const float* O    = (const float*)d_in[0];
    const float* T    = (const float*)d_in[1];
    const float* h_W0 = (const float*)d_in[2];
    const float* h_b0 = (const float*)d_in[3];
    const float* h_W1 = (const float*)d_in[4];
    const float* h_b1 = (const float*)d_in[5];
    const float* h_W2 = (const float*)d_in[6];
    const float* h_b2 = (const float*)d_in[7];
    const float* g_W0 = (const float*)d_in[8];
    const float* g_b0 = (const float*)d_in[9];
    const float* g_W1 = (const float*)d_in[10];
    const float* g_b1 = (const float*)d_in[11];
    const float* g_W2 = (const float*)d_in[12];
    const float* g_b2 = (const float*)d_in[13];
    const float* g_W3 = (const float*)d_in[14];
    const float* g_b3 = (const float*)d_in[15];
    const float* g_W4 = (const float*)d_in[16];
    const float* g_b4 = (const float*)d_in[17];

    int n_ctx = in_sizes[0] / 2;
    int n_tgt = in_sizes[1] / 2;

    float* ws           = (float*)d_ws;
    float* enc_partials = ws;                      // 32 * ENC_BLOCKS
    float* rW0          = ws + 32 * ENC_BLOCKS;    // 64
    float* lp_partials  = rW0 + 64;                // DEC_BLOCKS

    float* phi = (float*)d_out;                    // 2 * n_tgt
    float* lp  = (float*)d_out + (out_size - 1);   // scalar log_prob (last elt)

    enc_kernel<<<ENC_BLOCKS, BLOCK, 0, stream>>>(O, n_ctx, h_W0, h_b0, h_W1, h_b1,
                                                 enc_partials);
    mid_kernel<<<1, 128, 0, stream>>>(enc_partials, n_ctx, h_W2, h_b2, g_W0, g_b0,
                                      rW0);
    dec_kernel<<<DEC_BLOCKS, BLOCK, 0, stream>>>(T, n_tgt, rW0, g_W0 + 128 * 64,
                                                 g_W1, g_b1, g_W2, g_b2,
                                                 g_W3, g_b3, g_W4, g_b4,
                                                 phi, lp_partials);
    fin_kernel<<<1, 256, 0, stream>>>(lp_partials, DEC_BLOCKS, n_tgt, lp);
}

// Round 5
// 229.210 us; speedup vs baseline: 1.0128x; 1.0128x over previous
//
#include <hip/hip_runtime.h>
#include <math.h>

#define ENC_R 4
#define ENC_BLOCK 64
#define DEC_R 4
#define DEC_BLOCK 64

#define HALF_LOG_2PI 0.91893853320467274178f

// ---------------------------------------------------------------------------
// Kernel 1: encoder. MLP 2->8(relu)->32(relu), accumulate 32-dim activation
// sum. Weights staged in LDS (broadcast reads, conflict-free); each thread
// processes ENC_R rows so one ds_read_b128 weight quad feeds 4*ENC_R FMAs.
// Last encoder layer (32->128, linear) folded into kernel 2 (mean commutes).
// ---------------------------------------------------------------------------
__global__ __launch_bounds__(ENC_BLOCK) void enc_kernel(
    const float* __restrict__ O, int n_ctx,
    const float* __restrict__ W0, const float* __restrict__ b0,
    const float* __restrict__ W1, const float* __restrict__ b1,
    float* __restrict__ partials)
{
    __shared__ __align__(16) float sW0[16];
    __shared__ __align__(16) float sB0[8];
    __shared__ __align__(16) float sW1[256];
    __shared__ __align__(16) float sB1[32];
    int tid = threadIdx.x;
    if (tid < 16) sW0[tid] = W0[tid];
    if (tid < 8)  sB0[tid] = b0[tid];
    ((float4*)sW1)[tid] = ((const float4*)W1)[tid];   // 64 quads = 256 floats
    if (tid < 32) sB1[tid] = b1[tid];
    __syncthreads();

    int base = blockIdx.x * (ENC_BLOCK * ENC_R);
    float ox[ENC_R], oy[ENC_R];
    bool valid[ENC_R];
#pragma unroll
    for (int r = 0; r < ENC_R; ++r) {
        int row = base + r * ENC_BLOCK + tid;
        valid[r] = row < n_ctx;
        float2 o = valid[r] ? ((const float2*)O)[row] : make_float2(0.f, 0.f);
        ox[r] = o.x; oy[r] = o.y;
    }

    float a1[ENC_R][32];
#pragma unroll
    for (int r = 0; r < ENC_R; ++r)
#pragma unroll
        for (int k = 0; k < 32; ++k) a1[r][k] = sB1[k];

#pragma unroll
    for (int j = 0; j < 8; ++j) {
        float w0x = sW0[j], w0y = sW0[8 + j], bb = sB0[j];
        float a0[ENC_R];
#pragma unroll
        for (int r = 0; r < ENC_R; ++r)
            a0[r] = fmaxf(fmaf(ox[r], w0x, fmaf(oy[r], w0y, bb)), 0.f);
#pragma unroll
        for (int kq = 0; kq < 8; ++kq) {
            float4 w = ((const float4*)sW1)[j * 8 + kq];
#pragma unroll
            for (int r = 0; r < ENC_R; ++r) {
                a1[r][kq * 4 + 0] = fmaf(a0[r], w.x, a1[r][kq * 4 + 0]);
                a1[r][kq * 4 + 1] = fmaf(a0[r], w.y, a1[r][kq * 4 + 1]);
                a1[r][kq * 4 + 2] = fmaf(a0[r], w.z, a1[r][kq * 4 + 2]);
                a1[r][kq * 4 + 3] = fmaf(a0[r], w.w, a1[r][kq * 4 + 3]);
            }
        }
    }

    float acc[32];
#pragma unroll
    for (int k = 0; k < 32; ++k) acc[k] = 0.f;
#pragma unroll
    for (int r = 0; r < ENC_R; ++r)
#pragma unroll
        for (int k = 0; k < 32; ++k)
            acc[k] += valid[r] ? fmaxf(a1[r][k], 0.f) : 0.f;

    // one wave per block: butterfly-reduce each of the 32 sums, lane 0 stores
#pragma unroll
    for (int k = 0; k < 32; ++k) {
        float v = acc[k];
#pragma unroll
        for (int m = 32; m >= 1; m >>= 1) v += __shfl_xor(v, m, 64);
        if (tid == 0) partials[blockIdx.x * 32 + k] = v;
    }
}

// ---------------------------------------------------------------------------
// Kernel 2 (single block, 128 threads):
//   a2mean = (sum of encoder partials)/n_ctx            (32)
//   r      = a2mean @ h_W2 + h_b2                       (128)
//   rW0    = r @ g_W0[:128,:] + g_b0  -> ws             (64)
// ---------------------------------------------------------------------------
__global__ __launch_bounds__(128) void mid_kernel(
    const float* __restrict__ partials, int nblocks, int n_ctx,
    const float* __restrict__ hW2, const float* __restrict__ hb2,
    const float* __restrict__ gW0, const float* __restrict__ gb0,
    float* __restrict__ rW0out)
{
    __shared__ float a2m[32];
    __shared__ float rl[128];
    int t = threadIdx.x;
    if (t < 32) {
        float s = 0.f;
        for (int b = 0; b < nblocks; ++b) s += partials[b * 32 + t];
        a2m[t] = s / (float)n_ctx;
    }
    __syncthreads();
    {
        float s = hb2[t];
#pragma unroll
        for (int j = 0; j < 32; ++j) s = fmaf(a2m[j], hW2[j * 128 + t], s);
        rl[t] = s;
    }
    __syncthreads();
    if (t < 64) {
        float s = gb0[t];
#pragma unroll
        for (int i = 0; i < 128; ++i) s = fmaf(rl[i], gW0[i * 64 + t], s);
        rW0out[t] = s;
    }
}

// ---------------------------------------------------------------------------
// Kernel 3: decoder. All weights staged in LDS (11.6 KB, broadcast reads).
// Each thread handles DEC_R rows; one weight quad (ds_read_b128) feeds
// 4*DEC_R FMAs -> VALU-bound inner loop. Layer 0 collapses to
// relu(rW0 + x*g_W0[128,:]). Block = 1 wave.
// ---------------------------------------------------------------------------
__global__ __launch_bounds__(DEC_BLOCK) void dec_kernel(
    const float* __restrict__ T, int n_tgt,
    const float* __restrict__ rW0, const float* __restrict__ gW0last,
    const float* __restrict__ W1, const float* __restrict__ b1,
    const float* __restrict__ W2, const float* __restrict__ b2,
    const float* __restrict__ W3, const float* __restrict__ b3,
    const float* __restrict__ W4, const float* __restrict__ b4,
    float* __restrict__ phi, float* __restrict__ lp_partials)
{
    __shared__ __align__(16) float2 sL0[64];      // (rW0[j], gW0last[j])
    __shared__ __align__(16) float sW1[2048];
    __shared__ __align__(16) float sB1[32];
    __shared__ __align__(16) float sW2[512];
    __shared__ __align__(16) float sB2[16];
    __shared__ __align__(16) float sW3[128];
    __shared__ __align__(16) float sB3[8];
    __shared__ __align__(16) float sW4[16];
    __shared__ __align__(16) float sB4[2];
    int tid = threadIdx.x;
#pragma unroll
    for (int q = 0; q < 8; ++q)
        ((float4*)sW1)[q * 64 + tid] = ((const float4*)W1)[q * 64 + tid];
#pragma unroll
    for (int q = 0; q < 2; ++q)
        ((float4*)sW2)[q * 64 + tid] = ((const float4*)W2)[q * 64 + tid];
    if (tid < 32) ((float4*)sW3)[tid] = ((const float4*)W3)[tid];
    if (tid < 32) sB1[tid] = b1[tid];
    if (tid < 16) sB2[tid] = b2[tid];
    if (tid < 8)  sB3[tid] = b3[tid];
    if (tid < 16) sW4[tid] = W4[tid];
    if (tid < 2)  sB4[tid] = b4[tid];
    sL0[tid] = make_float2(rW0[tid], gW0last[tid]);
    __syncthreads();

    int base = blockIdx.x * (DEC_BLOCK * DEC_R);
    float x[DEC_R], y[DEC_R];
    bool valid[DEC_R];
#pragma unroll
    for (int r = 0; r < DEC_R; ++r) {
        int row = base + r * DEC_BLOCK + tid;
        valid[r] = row < n_tgt;
        float2 t2 = valid[r] ? ((const float2*)T)[row] : make_float2(0.f, 0.f);
        x[r] = t2.x; y[r] = t2.y;
    }

    // layer 1: 64 -> 32 (fused layer-0 activation)
    float a1[DEC_R][32];
#pragma unroll
    for (int r = 0; r < DEC_R; ++r)
#pragma unroll
        for (int k = 0; k < 32; ++k) a1[r][k] = sB1[k];

#pragma unroll 4
    for (int j = 0; j < 64; ++j) {
        float2 l0 = sL0[j];
        float a0[DEC_R];
#pragma unroll
        for (int r = 0; r < DEC_R; ++r)
            a0[r] = fmaxf(fmaf(x[r], l0.y, l0.x), 0.f);
#pragma unroll
        for (int kq = 0; kq < 8; ++kq) {
            float4 w = ((const float4*)sW1)[j * 8 + kq];
#pragma unroll
            for (int r = 0; r < DEC_R; ++r) {
                a1[r][kq * 4 + 0] = fmaf(a0[r], w.x, a1[r][kq * 4 + 0]);
                a1[r][kq * 4 + 1] = fmaf(a0[r], w.y, a1[r][kq * 4 + 1]);
                a1[r][kq * 4 + 2] = fmaf(a0[r], w.z, a1[r][kq * 4 + 2]);
                a1[r][kq * 4 + 3] = fmaf(a0[r], w.w, a1[r][kq * 4 + 3]);
            }
        }
    }
#pragma unroll
    for (int r = 0; r < DEC_R; ++r)
#pragma unroll
        for (int k = 0; k < 32; ++k) a1[r][k] = fmaxf(a1[r][k], 0.f);

    // layer 2: 32 -> 16
    float a2[DEC_R][16];
#pragma unroll
    for (int r = 0; r < DEC_R; ++r)
#pragma unroll
        for (int k = 0; k < 16; ++k) a2[r][k] = sB2[k];
#pragma unroll 8
    for (int j = 0; j < 32; ++j) {
#pragma unroll
        for (int kq = 0; kq < 4; ++kq) {
            float4 w = ((const float4*)sW2)[j * 4 + kq];
#pragma unroll
            for (int r = 0; r < DEC_R; ++r) {
                a2[r][kq * 4 + 0] = fmaf(a1[r][j], w.x, a2[r][kq * 4 + 0]);
                a2[r][kq * 4 + 1] = fmaf(a1[r][j], w.y, a2[r][kq * 4 + 1]);
                a2[r][kq * 4 + 2] = fmaf(a1[r][j], w.z, a2[r][kq * 4 + 2]);
                a2[r][kq * 4 + 3] = fmaf(a1[r][j], w.w, a2[r][kq * 4 + 3]);
            }
        }
    }
#pragma unroll
    for (int r = 0; r < DEC_R; ++r)
#pragma unroll
        for (int k = 0; k < 16; ++k) a2[r][k] = fmaxf(a2[r][k], 0.f);

    // layer 3: 16 -> 8
    float a3[DEC_R][8];
#pragma unroll
    for (int r = 0; r < DEC_R; ++r)
#pragma unroll
        for (int k = 0; k < 8; ++k) a3[r][k] = sB3[k];
#pragma unroll
    for (int j = 0; j < 16; ++j) {
#pragma unroll
        for (int kq = 0; kq < 2; ++kq) {
            float4 w = ((const float4*)sW3)[j * 2 + kq];
#pragma unroll
            for (int r = 0; r < DEC_R; ++r) {
                a3[r][kq * 4 + 0] = fmaf(a2[r][j], w.x, a3[r][kq * 4 + 0]);
                a3[r][kq * 4 + 1] = fmaf(a2[r][j], w.y, a3[r][kq * 4 + 1]);
                a3[r][kq * 4 + 2] = fmaf(a2[r][j], w.z, a3[r][kq * 4 + 2]);
                a3[r][kq * 4 + 3] = fmaf(a2[r][j], w.w, a3[r][kq * 4 + 3]);
            }
        }
    }

    // layer 4: 8 -> 2, phi store, log-prob
    float lp_acc = 0.f;
#pragma unroll
    for (int r = 0; r < DEC_R; ++r) {
        float p0 = sB4[0], p1 = sB4[1];
#pragma unroll
        for (int j = 0; j < 8; ++j) {
            float aj = fmaxf(a3[r][j], 0.f);
            p0 = fmaf(aj, sW4[j * 2 + 0], p0);
            p1 = fmaf(aj, sW4[j * 2 + 1], p1);
        }
        int row = base + r * DEC_BLOCK + tid;
        if (valid[r]) {
            ((float2*)phi)[row] = make_float2(p0, p1);
            // stable softplus: max(x,0)+log1p(exp(-|x|)) (== jax.nn.softplus)
            float sp = fmaxf(p1, 0.f) + log1pf(expf(-fabsf(p1)));
            float z = (y[r] - p0) / sp;
            lp_acc += fmaf(-0.5f * z, z, -logf(sp)) - HALF_LOG_2PI;
        }
    }

    // one wave per block: butterfly reduce, lane 0 stores
#pragma unroll
    for (int m = 32; m >= 1; m >>= 1) lp_acc += __shfl_xor(lp_acc, m, 64);
    if (tid == 0) lp_partials[blockIdx.x] = lp_acc;
}

// ---------------------------------------------------------------------------
// Kernel 4: reduce per-block logp partials -> mean -> last element of d_out
// ---------------------------------------------------------------------------
__global__ __launch_bounds__(256) void fin_kernel(
    const float* __restrict__ lp_partials, int nparts, int n_tgt,
    float* __restrict__ out)
{
    __shared__ float red[256];
    float s = 0.f;
    for (int i = threadIdx.x; i < nparts; i += 256) s += lp_partials[i];
    red[threadIdx.x] = s;
    __syncthreads();
    for (int o = 128; o > 0; o >>= 1) {
        if (threadIdx.x < o) red[threadIdx.x] += red[threadIdx.x + o];
        __syncthreads();
    }
    if (threadIdx.x == 0) out[0] = red[0] / (float)n_tgt;
}

extern "C" void kernel_launch(void* const* d_in, const int* in_sizes, int n_in,
                              void* d_out, int out_size, void* d_ws, size_t ws_size,
                              hipStream_t stream)
{
    const float* O    = (const float*)d_in[0];
    const float* T    = (const float*)d_in[1];
    const float* h_W0 = (const float*)d_in[2];
    const float* h_b0 = (const float*)d_in[3];
    const float* h_W1 = (const float*)d_in[4];
    const float* h_b1 = (const float*)d_in[5];
    const float* h_W2 = (const float*)d_in[6];
    const float* h_b2 = (const float*)d_in[7];
    const float* g_W0 = (const float*)d_in[8];
    const float* g_b0 = (const float*)d_in[9];
    const float* g_W1 = (const float*)d_in[10];
    const float* g_b1 = (const float*)d_in[11];
    const float* g_W2 = (const float*)d_in[12];
    const float* g_b2 = (const float*)d_in[13];
    const float* g_W3 = (const float*)d_in[14];
    const float* g_b3 = (const float*)d_in[15];
    const float* g_W4 = (const float*)d_in[16];
    const float* g_b4 = (const float*)d_in[17];

    int n_ctx = in_sizes[0] / 2;
    int n_tgt = in_sizes[1] / 2;

    int enc_blocks = (n_ctx + ENC_BLOCK * ENC_R - 1) / (ENC_BLOCK * ENC_R);
    int dec_blocks = (n_tgt + DEC_BLOCK * DEC_R - 1) / (DEC_BLOCK * DEC_R);

    float* ws           = (float*)d_ws;
    float* enc_partials = ws;                          // 32 * enc_blocks
    float* rW0          = ws + 32 * enc_blocks;        // 64
    float* lp_partials  = rW0 + 64;                    // dec_blocks

    float* phi = (float*)d_out;                        // 2 * n_tgt
    float* lp  = (float*)d_out + (out_size - 1);       // scalar log_prob

    enc_kernel<<<enc_blocks, ENC_BLOCK, 0, stream>>>(O, n_ctx, h_W0, h_b0,
                                                     h_W1, h_b1, enc_partials);
    mid_kernel<<<1, 128, 0, stream>>>(enc_partials, enc_blocks, n_ctx,
                                      h_W2, h_b2, g_W0, g_b0, rW0);
    dec_kernel<<<dec_blocks, DEC_BLOCK, 0, stream>>>(T, n_tgt, rW0,
                                                     g_W0 + 128 * 64,
                                                     g_W1, g_b1, g_W2, g_b2,
                                                     g_W3, g_b3, g_W4, g_b4,
                                                     phi, lp_partials);
    fin_kernel<<<1, 256, 0, stream>>>(lp_partials, dec_blocks, n_tgt, lp);
}

// Round 11
// 140.301 us; speedup vs baseline: 1.6546x; 1.6337x over previous
//
#include <hip/hip_runtime.h>
#include <math.h>

#define ENC_R 2
#define ENC_BLOCK 64
#define DEC_R 2
#define DEC_BLOCK 64
#define MID_T 1024
#define MID_CHUNKS 32

#define HALF_LOG_2PI 0.91893853320467274178f

// ---------------------------------------------------------------------------
// Kernel 1: encoder. MLP 2->8(relu)->32(relu), accumulate 32-dim activation
// sum. Weights staged in LDS (broadcast reads, conflict-free); each thread
// processes ENC_R rows so one weight quad feeds 4*ENC_R FMAs.
// ENC_R=2 (was 4): R=4's a1[4][32]+acc[32] live set spilled to scratch.
// Last encoder layer (32->128, linear) folded into kernel 2 (mean commutes).
// ---------------------------------------------------------------------------
__global__ __launch_bounds__(ENC_BLOCK) void enc_kernel(
    const float* __restrict__ O, int n_ctx,
    const float* __restrict__ W0, const float* __restrict__ b0,
    const float* __restrict__ W1, const float* __restrict__ b1,
    float* __restrict__ partials)
{
    __shared__ __align__(16) float sW0[16];
    __shared__ __align__(16) float sB0[8];
    __shared__ __align__(16) float sW1[256];
    __shared__ __align__(16) float sB1[32];
    int tid = threadIdx.x;
    if (tid < 16) sW0[tid] = W0[tid];
    if (tid < 8)  sB0[tid] = b0[tid];
    ((float4*)sW1)[tid] = ((const float4*)W1)[tid];   // 64 quads = 256 floats
    if (tid < 32) sB1[tid] = b1[tid];
    __syncthreads();

    int base = blockIdx.x * (ENC_BLOCK * ENC_R);
    float ox[ENC_R], oy[ENC_R];
    bool valid[ENC_R];
#pragma unroll
    for (int r = 0; r < ENC_R; ++r) {
        int row = base + r * ENC_BLOCK + tid;
        valid[r] = row < n_ctx;
        float2 o = valid[r] ? ((const float2*)O)[row] : make_float2(0.f, 0.f);
        ox[r] = o.x; oy[r] = o.y;
    }

    float a1[ENC_R][32];
#pragma unroll
    for (int r = 0; r < ENC_R; ++r)
#pragma unroll
        for (int k = 0; k < 32; ++k) a1[r][k] = sB1[k];

#pragma unroll
    for (int j = 0; j < 8; ++j) {
        float w0x = sW0[j], w0y = sW0[8 + j], bb = sB0[j];
        float a0[ENC_R];
#pragma unroll
        for (int r = 0; r < ENC_R; ++r)
            a0[r] = fmaxf(fmaf(ox[r], w0x, fmaf(oy[r], w0y, bb)), 0.f);
#pragma unroll
        for (int kq = 0; kq < 8; ++kq) {
            float4 w = ((const float4*)sW1)[j * 8 + kq];
#pragma unroll
            for (int r = 0; r < ENC_R; ++r) {
                a1[r][kq * 4 + 0] = fmaf(a0[r], w.x, a1[r][kq * 4 + 0]);
                a1[r][kq * 4 + 1] = fmaf(a0[r], w.y, a1[r][kq * 4 + 1]);
                a1[r][kq * 4 + 2] = fmaf(a0[r], w.z, a1[r][kq * 4 + 2]);
                a1[r][kq * 4 + 3] = fmaf(a0[r], w.w, a1[r][kq * 4 + 3]);
            }
        }
    }

    float acc[32];
#pragma unroll
    for (int k = 0; k < 32; ++k) acc[k] = 0.f;
#pragma unroll
    for (int r = 0; r < ENC_R; ++r)
#pragma unroll
        for (int k = 0; k < 32; ++k)
            acc[k] += valid[r] ? fmaxf(a1[r][k], 0.f) : 0.f;

    // one wave per block: butterfly-reduce each of the 32 sums, lane 0 stores
#pragma unroll
    for (int k = 0; k < 32; ++k) {
        float v = acc[k];
#pragma unroll
        for (int m = 32; m >= 1; m >>= 1) v += __shfl_xor(v, m, 64);
        if (tid == 0) partials[blockIdx.x * 32 + k] = v;
    }
}

// ---------------------------------------------------------------------------
// Kernel 2 (single block, MID_T=1024 threads):
//   stage A: parallel reduction of enc partials (32 chunks x 32 k), LDS tree
//   stage B: a2mean -> r = a2mean @ h_W2 + h_b2          (128)
//   stage C: rW0 = r @ g_W0[:128,:] + g_b0 -> ws         (64)
// Round-5 profile showed the old 1-thread-per-k serial loop at 97us with
// VALUBusy ~0 (391 dependent ~245cyc loads). 32-way chunk parallelism cuts
// the per-thread load count to ~25 independent loads.
// ---------------------------------------------------------------------------
__global__ __launch_bounds__(MID_T) void mid_kernel(
    const float* __restrict__ partials, int nblocks, int n_ctx,
    const float* __restrict__ hW2, const float* __restrict__ hb2,
    const float* __restrict__ gW0, const float* __restrict__ gb0,
    float* __restrict__ rW0out)
{
    __shared__ float chunk[MID_CHUNKS][32];
    __shared__ float a2m[32];
    __shared__ float rl[128];
    int t = threadIdx.x;
    int k = t & 31, c = t >> 5;            // MID_CHUNKS chunks x 32 k-lanes
    float s = 0.f;
    for (int b = c; b < nblocks; b += MID_CHUNKS) s += partials[b * 32 + k];
    chunk[c][k] = s;
    __syncthreads();
    if (t < 32) {
        float v = 0.f;
#pragma unroll
        for (int cc = 0; cc < MID_CHUNKS; ++cc) v += chunk[cc][t];
        a2m[t] = v / (float)n_ctx;
    }
    __syncthreads();
    if (t < 128) {
        float v = hb2[t];
#pragma unroll
        for (int j = 0; j < 32; ++j) v = fmaf(a2m[j], hW2[j * 128 + t], v);
        rl[t] = v;
    }
    __syncthreads();
    if (t < 64) {
        float v = gb0[t];
#pragma unroll
        for (int i = 0; i < 128; ++i) v = fmaf(rl[i], gW0[i * 64 + t], v);
        rW0out[t] = v;
    }
}

// ---------------------------------------------------------------------------
// Kernel 3: decoder. All weights staged in LDS (11.6 KB, broadcast reads).
// Each thread handles DEC_R rows; one weight quad feeds 4*DEC_R FMAs.
// DEC_R=2 (was 4): R=4's a1[4][32]+a2[4][16]+a3[4][8] = 224+ VGPR live set
// spilled to scratch (theory for the ~90us r5 duration). R=2 peaks ~130 VGPR
// and doubles waves/CU (6) for latency hiding.
// Layer 0 collapses to relu(rW0 + x*g_W0[128,:]). Block = 1 wave.
// ---------------------------------------------------------------------------
__global__ __launch_bounds__(DEC_BLOCK) void dec_kernel(
    const float* __restrict__ T, int n_tgt,
    const float* __restrict__ rW0, const float* __restrict__ gW0last,
    const float* __restrict__ W1, const float* __restrict__ b1,
    const float* __restrict__ W2, const float* __restrict__ b2,
    const float* __restrict__ W3, const float* __restrict__ b3,
    const float* __restrict__ W4, const float* __restrict__ b4,
    float* __restrict__ phi, float* __restrict__ lp_partials)
{
    __shared__ __align__(16) float2 sL0[64];      // (rW0[j], gW0last[j])
    __shared__ __align__(16) float sW1[2048];
    __shared__ __align__(16) float sB1[32];
    __shared__ __align__(16) float sW2[512];
    __shared__ __align__(16) float sB2[16];
    __shared__ __align__(16) float sW3[128];
    __shared__ __align__(16) float sB3[8];
    __shared__ __align__(16) float sW4[16];
    __shared__ __align__(16) float sB4[2];
    int tid = threadIdx.x;
#pragma unroll
    for (int q = 0; q < 8; ++q)
        ((float4*)sW1)[q * 64 + tid] = ((const float4*)W1)[q * 64 + tid];
#pragma unroll
    for (int q = 0; q < 2; ++q)
        ((float4*)sW2)[q * 64 + tid] = ((const float4*)W2)[q * 64 + tid];
    if (tid < 32) ((float4*)sW3)[tid] = ((const float4*)W3)[tid];
    if (tid < 32) sB1[tid] = b1[tid];
    if (tid < 16) sB2[tid] = b2[tid];
    if (tid < 8)  sB3[tid] = b3[tid];
    if (tid < 16) sW4[tid] = W4[tid];
    if (tid < 2)  sB4[tid] = b4[tid];
    sL0[tid] = make_float2(rW0[tid], gW0last[tid]);
    __syncthreads();

    int base = blockIdx.x * (DEC_BLOCK * DEC_R);
    float x[DEC_R], y[DEC_R];
    bool valid[DEC_R];
#pragma unroll
    for (int r = 0; r < DEC_R; ++r) {
        int row = base + r * DEC_BLOCK + tid;
        valid[r] = row < n_tgt;
        float2 t2 = valid[r] ? ((const float2*)T)[row] : make_float2(0.f, 0.f);
        x[r] = t2.x; y[r] = t2.y;
    }

    // layer 1: 64 -> 32 (fused layer-0 activation)
    float a1[DEC_R][32];
#pragma unroll
    for (int r = 0; r < DEC_R; ++r)
#pragma unroll
        for (int k = 0; k < 32; ++k) a1[r][k] = sB1[k];

#pragma unroll 4
    for (int j = 0; j < 64; ++j) {
        float2 l0 = sL0[j];
        float a0[DEC_R];
#pragma unroll
        for (int r = 0; r < DEC_R; ++r)
            a0[r] = fmaxf(fmaf(x[r], l0.y, l0.x), 0.f);
#pragma unroll
        for (int kq = 0; kq < 8; ++kq) {
            float4 w = ((const float4*)sW1)[j * 8 + kq];
#pragma unroll
            for (int r = 0; r < DEC_R; ++r) {
                a1[r][kq * 4 + 0] = fmaf(a0[r], w.x, a1[r][kq * 4 + 0]);
                a1[r][kq * 4 + 1] = fmaf(a0[r], w.y, a1[r][kq * 4 + 1]);
                a1[r][kq * 4 + 2] = fmaf(a0[r], w.z, a1[r][kq * 4 + 2]);
                a1[r][kq * 4 + 3] = fmaf(a0[r], w.w, a1[r][kq * 4 + 3]);
            }
        }
    }
#pragma unroll
    for (int r = 0; r < DEC_R; ++r)
#pragma unroll
        for (int k = 0; k < 32; ++k) a1[r][k] = fmaxf(a1[r][k], 0.f);

    // layer 2: 32 -> 16
    float a2[DEC_R][16];
#pragma unroll
    for (int r = 0; r < DEC_R; ++r)
#pragma unroll
        for (int k = 0; k < 16; ++k) a2[r][k] = sB2[k];
#pragma unroll 8
    for (int j = 0; j < 32; ++j) {
#pragma unroll
        for (int kq = 0; kq < 4; ++kq) {
            float4 w = ((const float4*)sW2)[j * 4 + kq];
#pragma unroll
            for (int r = 0; r < DEC_R; ++r) {
                a2[r][kq * 4 + 0] = fmaf(a1[r][j], w.x, a2[r][kq * 4 + 0]);
                a2[r][kq * 4 + 1] = fmaf(a1[r][j], w.y, a2[r][kq * 4 + 1]);
                a2[r][kq * 4 + 2] = fmaf(a1[r][j], w.z, a2[r][kq * 4 + 2]);
                a2[r][kq * 4 + 3] = fmaf(a1[r][j], w.w, a2[r][kq * 4 + 3]);
            }
        }
    }
#pragma unroll
    for (int r = 0; r < DEC_R; ++r)
#pragma unroll
        for (int k = 0; k < 16; ++k) a2[r][k] = fmaxf(a2[r][k], 0.f);

    // layer 3: 16 -> 8
    float a3[DEC_R][8];
#pragma unroll
    for (int r = 0; r < DEC_R; ++r)
#pragma unroll
        for (int k = 0; k < 8; ++k) a3[r][k] = sB3[k];
#pragma unroll
    for (int j = 0; j < 16; ++j) {
#pragma unroll
        for (int kq = 0; kq < 2; ++kq) {
            float4 w = ((const float4*)sW3)[j * 2 + kq];
#pragma unroll
            for (int r = 0; r < DEC_R; ++r) {
                a3[r][kq * 4 + 0] = fmaf(a2[r][j], w.x, a3[r][kq * 4 + 0]);
                a3[r][kq * 4 + 1] = fmaf(a2[r][j], w.y, a3[r][kq * 4 + 1]);
                a3[r][kq * 4 + 2] = fmaf(a2[r][j], w.z, a3[r][kq * 4 + 2]);
                a3[r][kq * 4 + 3] = fmaf(a2[r][j], w.w, a3[r][kq * 4 + 3]);
            }
        }
    }

    // layer 4: 8 -> 2, phi store, log-prob
    float lp_acc = 0.f;
#pragma unroll
    for (int r = 0; r < DEC_R; ++r) {
        float p0 = sB4[0], p1 = sB4[1];
#pragma unroll
        for (int j = 0; j < 8; ++j) {
            float aj = fmaxf(a3[r][j], 0.f);
            p0 = fmaf(aj, sW4[j * 2 + 0], p0);
            p1 = fmaf(aj, sW4[j * 2 + 1], p1);
        }
        int row = base + r * DEC_BLOCK + tid;
        if (valid[r]) {
            ((float2*)phi)[row] = make_float2(p0, p1);
            // stable softplus: max(x,0)+log1p(exp(-|x|)) (== jax.nn.softplus)
            float sp = fmaxf(p1, 0.f) + log1pf(expf(-fabsf(p1)));
            float z = (y[r] - p0) / sp;
            lp_acc += fmaf(-0.5f * z, z, -logf(sp)) - HALF_LOG_2PI;
        }
    }

    // one wave per block: butterfly reduce, lane 0 stores
#pragma unroll
    for (int m = 32; m >= 1; m >>= 1) lp_acc += __shfl_xor(lp_acc, m, 64);
    if (tid == 0) lp_partials[blockIdx.x] = lp_acc;
}

// ---------------------------------------------------------------------------
// Kernel 4: reduce per-block logp partials -> mean -> last element of d_out
// ---------------------------------------------------------------------------
__global__ __launch_bounds__(256) void fin_kernel(
    const float* __restrict__ lp_partials, int nparts, int n_tgt,
    float* __restrict__ out)
{
    __shared__ float red[256];
    float s = 0.f;
    for (int i = threadIdx.x; i < nparts; i += 256) s += lp_partials[i];
    red[threadIdx.x] = s;
    __syncthreads();
    for (int o = 128; o > 0; o >>= 1) {
        if (threadIdx.x < o) red[threadIdx.x] += red[threadIdx.x + o];
        __syncthreads();
    }
    if (threadIdx.x == 0) out[0] = red[0] / (float)n_tgt;
}

extern "C" void kernel_launch(void* const* d_in, const int* in_sizes, int n_in,
                              void* d_out, int out_size, void* d_ws, size_t ws_size,
                              hipStream_t stream)
{
    const float* O    = (const float*)d_in[0];
    const float* T    = (const float*)d_in[1];
    const float* h_W0 = (const float*)d_in[2];
    const float* h_b0 = (const float*)d_in[3];
    const float* h_W1 = (const float*)d_in[4];
    const float* h_b1 = (const float*)d_in[5];
    const float* h_W2 = (const float*)d_in[6];
    const float* h_b2 = (const float*)d_in[7];
    const float* g_W0 = (const float*)d_in[8];
    const float* g_b0 = (const float*)d_in[9];
    const float* g_W1 = (const float*)d_in[10];
    const float* g_b1 = (const float*)d_in[11];
    const float* g_W2 = (const float*)d_in[12];
    const float* g_b2 = (const float*)d_in[13];
    const float* g_W3 = (const float*)d_in[14];
    const float* g_b3 = (const float*)d_in[15];
    const float* g_W4 = (const float*)d_in[16];
    const float* g_b4 = (const float*)d_in[17];

    int n_ctx = in_sizes[0] / 2;
    int n_tgt = in_sizes[1] / 2;

    int enc_blocks = (n_ctx + ENC_BLOCK * ENC_R - 1) / (ENC_BLOCK * ENC_R);
    int dec_blocks = (n_tgt + DEC_BLOCK * DEC_R - 1) / (DEC_BLOCK * DEC_R);

    float* ws           = (float*)d_ws;
    float* enc_partials = ws;                          // 32 * enc_blocks
    float* rW0          = ws + 32 * enc_blocks;        // 64
    float* lp_partials  = rW0 + 64;                    // dec_blocks

    float* phi = (float*)d_out;                        // 2 * n_tgt
    float* lp  = (float*)d_out + (out_size - 1);       // scalar log_prob

    enc_kernel<<<enc_blocks, ENC_BLOCK, 0, stream>>>(O, n_ctx, h_W0, h_b0,
                                                     h_W1, h_b1, enc_partials);
    mid_kernel<<<1, MID_T, 0, stream>>>(enc_partials, enc_blocks, n_ctx,
                                        h_W2, h_b2, g_W0, g_b0, rW0);
    dec_kernel<<<dec_blocks, DEC_BLOCK, 0, stream>>>(T, n_tgt, rW0,
                                                     g_W0 + 128 * 64,
                                                     g_W1, g_b1, g_W2, g_b2,
                                                     g_W3, g_b3, g_W4, g_b4,
                                                     phi, lp_partials);
    fin_kernel<<<1, 256, 0, stream>>>(lp_partials, dec_blocks, n_tgt, lp);
}

// Round 13
// 128.171 us; speedup vs baseline: 1.8112x; 1.0946x over previous
//
#include <hip/hip_runtime.h>
#include <math.h>

#define ENC_R 2
#define ENC_BLOCK 256
#define DEC_R 2
#define DEC_BLOCK 256
#define MID_T 1024
#define MID_CHUNKS 32

#define HALF_LOG_2PI 0.91893853320467274178f

// ---------------------------------------------------------------------------
// Kernel 1: encoder. MLP 2->8(relu)->32(relu), accumulate 32-dim activation
// sum. Weights staged in LDS; 256-thread blocks (4 waves) amortize staging.
// Each thread processes ENC_R=2 rows. Last encoder layer (32->128, linear)
// folded into kernel 2 (mean commutes with linear).
// ---------------------------------------------------------------------------
__global__ __launch_bounds__(ENC_BLOCK) void enc_kernel(
    const float* __restrict__ O, int n_ctx,
    const float* __restrict__ W0, const float* __restrict__ b0,
    const float* __restrict__ W1, const float* __restrict__ b1,
    float* __restrict__ partials)
{
    __shared__ __align__(16) float sW0[16];
    __shared__ __align__(16) float sB0[8];
    __shared__ __align__(16) float sW1[256];
    __shared__ __align__(16) float sB1[32];
    int tid = threadIdx.x;
    if (tid < 16) sW0[tid] = W0[tid];
    if (tid < 8)  sB0[tid] = b0[tid];
    if (tid < 64) ((float4*)sW1)[tid] = ((const float4*)W1)[tid];
    if (tid < 32) sB1[tid] = b1[tid];
    __syncthreads();

    int base = blockIdx.x * (ENC_BLOCK * ENC_R);
    float ox[ENC_R], oy[ENC_R];
    bool valid[ENC_R];
#pragma unroll
    for (int r = 0; r < ENC_R; ++r) {
        int row = base + r * ENC_BLOCK + tid;
        valid[r] = row < n_ctx;
        float2 o = valid[r] ? ((const float2*)O)[row] : make_float2(0.f, 0.f);
        ox[r] = o.x; oy[r] = o.y;
    }

    float a1[ENC_R][32];
#pragma unroll
    for (int r = 0; r < ENC_R; ++r)
#pragma unroll
        for (int k = 0; k < 32; ++k) a1[r][k] = sB1[k];

#pragma unroll
    for (int j = 0; j < 8; ++j) {
        float w0x = sW0[j], w0y = sW0[8 + j], bb = sB0[j];
        float a0[ENC_R];
#pragma unroll
        for (int r = 0; r < ENC_R; ++r)
            a0[r] = fmaxf(fmaf(ox[r], w0x, fmaf(oy[r], w0y, bb)), 0.f);
#pragma unroll
        for (int kq = 0; kq < 8; ++kq) {
            float4 w = ((const float4*)sW1)[j * 8 + kq];
#pragma unroll
            for (int r = 0; r < ENC_R; ++r) {
                a1[r][kq * 4 + 0] = fmaf(a0[r], w.x, a1[r][kq * 4 + 0]);
                a1[r][kq * 4 + 1] = fmaf(a0[r], w.y, a1[r][kq * 4 + 1]);
                a1[r][kq * 4 + 2] = fmaf(a0[r], w.z, a1[r][kq * 4 + 2]);
                a1[r][kq * 4 + 3] = fmaf(a0[r], w.w, a1[r][kq * 4 + 3]);
            }
        }
    }

    float acc[32];
#pragma unroll
    for (int k = 0; k < 32; ++k) acc[k] = 0.f;
#pragma unroll
    for (int r = 0; r < ENC_R; ++r)
#pragma unroll
        for (int k = 0; k < 32; ++k)
            acc[k] += valid[r] ? fmaxf(a1[r][k], 0.f) : 0.f;

    // per-wave butterfly reduce each of the 32 sums, then cross-wave via LDS
#pragma unroll
    for (int k = 0; k < 32; ++k) {
        float v = acc[k];
#pragma unroll
        for (int m = 32; m >= 1; m >>= 1) v += __shfl_xor(v, m, 64);
        acc[k] = v;
    }
    __shared__ float red[ENC_BLOCK / 64][32];
    int lane = tid & 63, wv = tid >> 6;
    if (lane == 0) {
#pragma unroll
        for (int k = 0; k < 32; ++k) red[wv][k] = acc[k];
    }
    __syncthreads();
    if (tid < 32) {
        float s = 0.f;
#pragma unroll
        for (int w = 0; w < ENC_BLOCK / 64; ++w) s += red[w][tid];
        partials[blockIdx.x * 32 + tid] = s;
    }
}

// ---------------------------------------------------------------------------
// Kernel 2 (single block, MID_T=1024 threads):
//   stage A: parallel reduction of enc partials (32 chunks x 32 k), LDS tree
//   stage B: a2mean -> r = a2mean @ h_W2 + h_b2          (128)
//   stage C: rW0 = r @ g_W0[:128,:] + g_b0 -> ws         (64)
// (r5 profile: old serial loop was 97us, VALUBusy ~0 — dependent-load chain.)
// ---------------------------------------------------------------------------
__global__ __launch_bounds__(MID_T) void mid_kernel(
    const float* __restrict__ partials, int nblocks, int n_ctx,
    const float* __restrict__ hW2, const float* __restrict__ hb2,
    const float* __restrict__ gW0, const float* __restrict__ gb0,
    float* __restrict__ rW0out)
{
    __shared__ float chunk[MID_CHUNKS][32];
    __shared__ float a2m[32];
    __shared__ float rl[128];
    int t = threadIdx.x;
    int k = t & 31, c = t >> 5;            // MID_CHUNKS chunks x 32 k-lanes
    float s = 0.f;
    for (int b = c; b < nblocks; b += MID_CHUNKS) s += partials[b * 32 + k];
    chunk[c][k] = s;
    __syncthreads();
    if (t < 32) {
        float v = 0.f;
#pragma unroll
        for (int cc = 0; cc < MID_CHUNKS; ++cc) v += chunk[cc][t];
        a2m[t] = v / (float)n_ctx;
    }
    __syncthreads();
    if (t < 128) {
        float v = hb2[t];
#pragma unroll
        for (int j = 0; j < 32; ++j) v = fmaf(a2m[j], hW2[j * 128 + t], v);
        rl[t] = v;
    }
    __syncthreads();
    if (t < 64) {
        float v = gb0[t];
#pragma unroll
        for (int i = 0; i < 128; ++i) v = fmaf(rl[i], gW0[i * 64 + t], v);
        rW0out[t] = v;
    }
}

// ---------------------------------------------------------------------------
// Kernel 3: decoder. All weights staged in LDS (11.6 KB, broadcast reads);
// 256-thread blocks (4 waves) amortize staging 4x vs the r11 1-wave blocks
// (391 stagings instead of 1563). Each thread handles DEC_R=2 rows; one
// b128 weight quad feeds 8 FMAs (VALU-dominant inner loop). Layer 0
// collapses to relu(rW0 + x*g_W0[128,:]).
// ---------------------------------------------------------------------------
__global__ __launch_bounds__(DEC_BLOCK) void dec_kernel(
    const float* __restrict__ T, int n_tgt,
    const float* __restrict__ rW0, const float* __restrict__ gW0last,
    const float* __restrict__ W1, const float* __restrict__ b1,
    const float* __restrict__ W2, const float* __restrict__ b2,
    const float* __restrict__ W3, const float* __restrict__ b3,
    const float* __restrict__ W4, const float* __restrict__ b4,
    float* __restrict__ phi, float* __restrict__ lp_partials)
{
    __shared__ __align__(16) float2 sL0[64];      // (rW0[j], gW0last[j])
    __shared__ __align__(16) float sW1[2048];
    __shared__ __align__(16) float sB1[32];
    __shared__ __align__(16) float sW2[512];
    __shared__ __align__(16) float sB2[16];
    __shared__ __align__(16) float sW3[128];
    __shared__ __align__(16) float sB3[8];
    __shared__ __align__(16) float sW4[16];
    __shared__ __align__(16) float sB4[2];
    int tid = threadIdx.x;
#pragma unroll
    for (int q = 0; q < 2; ++q)
        ((float4*)sW1)[q * 256 + tid] = ((const float4*)W1)[q * 256 + tid];
    if (tid < 128) ((float4*)sW2)[tid] = ((const float4*)W2)[tid];
    if (tid < 32)  ((float4*)sW3)[tid] = ((const float4*)W3)[tid];
    if (tid < 32)  sB1[tid] = b1[tid];
    if (tid < 16)  sB2[tid] = b2[tid];
    if (tid < 8)   sB3[tid] = b3[tid];
    if (tid < 16)  sW4[tid] = W4[tid];
    if (tid < 2)   sB4[tid] = b4[tid];
    if (tid < 64)  sL0[tid] = make_float2(rW0[tid], gW0last[tid]);
    __syncthreads();

    int base = blockIdx.x * (DEC_BLOCK * DEC_R);
    float x[DEC_R], y[DEC_R];
    bool valid[DEC_R];
#pragma unroll
    for (int r = 0; r < DEC_R; ++r) {
        int row = base + r * DEC_BLOCK + tid;
        valid[r] = row < n_tgt;
        float2 t2 = valid[r] ? ((const float2*)T)[row] : make_float2(0.f, 0.f);
        x[r] = t2.x; y[r] = t2.y;
    }

    // layer 1: 64 -> 32 (fused layer-0 activation)
    float a1[DEC_R][32];
#pragma unroll
    for (int r = 0; r < DEC_R; ++r)
#pragma unroll
        for (int k = 0; k < 32; ++k) a1[r][k] = sB1[k];

#pragma unroll 4
    for (int j = 0; j < 64; ++j) {
        float2 l0 = sL0[j];
        float a0[DEC_R];
#pragma unroll
        for (int r = 0; r < DEC_R; ++r)
            a0[r] = fmaxf(fmaf(x[r], l0.y, l0.x), 0.f);
#pragma unroll
        for (int kq = 0; kq < 8; ++kq) {
            float4 w = ((const float4*)sW1)[j * 8 + kq];
#pragma unroll
            for (int r = 0; r < DEC_R; ++r) {
                a1[r][kq * 4 + 0] = fmaf(a0[r], w.x, a1[r][kq * 4 + 0]);
                a1[r][kq * 4 + 1] = fmaf(a0[r], w.y, a1[r][kq * 4 + 1]);
                a1[r][kq * 4 + 2] = fmaf(a0[r], w.z, a1[r][kq * 4 + 2]);
                a1[r][kq * 4 + 3] = fmaf(a0[r], w.w, a1[r][kq * 4 + 3]);
            }
        }
    }
#pragma unroll
    for (int r = 0; r < DEC_R; ++r)
#pragma unroll
        for (int k = 0; k < 32; ++k) a1[r][k] = fmaxf(a1[r][k], 0.f);

    // layer 2: 32 -> 16
    float a2[DEC_R][16];
#pragma unroll
    for (int r = 0; r < DEC_R; ++r)
#pragma unroll
        for (int k = 0; k < 16; ++k) a2[r][k] = sB2[k];
#pragma unroll 8
    for (int j = 0; j < 32; ++j) {
#pragma unroll
        for (int kq = 0; kq < 4; ++kq) {
            float4 w = ((const float4*)sW2)[j * 4 + kq];
#pragma unroll
            for (int r = 0; r < DEC_R; ++r) {
                a2[r][kq * 4 + 0] = fmaf(a1[r][j], w.x, a2[r][kq * 4 + 0]);
                a2[r][kq * 4 + 1] = fmaf(a1[r][j], w.y, a2[r][kq * 4 + 1]);
                a2[r][kq * 4 + 2] = fmaf(a1[r][j], w.z, a2[r][kq * 4 + 2]);
                a2[r][kq * 4 + 3] = fmaf(a1[r][j], w.w, a2[r][kq * 4 + 3]);
            }
        }
    }
#pragma unroll
    for (int r = 0; r < DEC_R; ++r)
#pragma unroll
        for (int k = 0; k < 16; ++k) a2[r][k] = fmaxf(a2[r][k], 0.f);

    // layer 3: 16 -> 8
    float a3[DEC_R][8];
#pragma unroll
    for (int r = 0; r < DEC_R; ++r)
#pragma unroll
        for (int k = 0; k < 8; ++k) a3[r][k] = sB3[k];
#pragma unroll
    for (int j = 0; j < 16; ++j) {
#pragma unroll
        for (int kq = 0; kq < 2; ++kq) {
            float4 w = ((const float4*)sW3)[j * 2 + kq];
#pragma unroll
            for (int r = 0; r < DEC_R; ++r) {
                a3[r][kq * 4 + 0] = fmaf(a2[r][j], w.x, a3[r][kq * 4 + 0]);
                a3[r][kq * 4 + 1] = fmaf(a2[r][j], w.y, a3[r][kq * 4 + 1]);
                a3[r][kq * 4 + 2] = fmaf(a2[r][j], w.z, a3[r][kq * 4 + 2]);
                a3[r][kq * 4 + 3] = fmaf(a2[r][j], w.w, a3[r][kq * 4 + 3]);
            }
        }
    }

    // layer 4: 8 -> 2, phi store, log-prob
    float lp_acc = 0.f;
#pragma unroll
    for (int r = 0; r < DEC_R; ++r) {
        float p0 = sB4[0], p1 = sB4[1];
#pragma unroll
        for (int j = 0; j < 8; ++j) {
            float aj = fmaxf(a3[r][j], 0.f);
            p0 = fmaf(aj, sW4[j * 2 + 0], p0);
            p1 = fmaf(aj, sW4[j * 2 + 1], p1);
        }
        int row = base + r * DEC_BLOCK + tid;
        if (valid[r]) {
            ((float2*)phi)[row] = make_float2(p0, p1);
            // stable softplus: max(x,0)+log1p(exp(-|x|)) (== jax.nn.softplus)
            float sp = fmaxf(p1, 0.f) + log1pf(expf(-fabsf(p1)));
            float z = (y[r] - p0) / sp;
            lp_acc += fmaf(-0.5f * z, z, -logf(sp)) - HALF_LOG_2PI;
        }
    }

    // per-wave butterfly reduce + cross-wave LDS reduce, thread 0 stores
#pragma unroll
    for (int m = 32; m >= 1; m >>= 1) lp_acc += __shfl_xor(lp_acc, m, 64);
    __shared__ float redl[DEC_BLOCK / 64];
    int lane = tid & 63, wv = tid >> 6;
    if (lane == 0) redl[wv] = lp_acc;
    __syncthreads();
    if (tid == 0) {
        float s = 0.f;
#pragma unroll
        for (int w = 0; w < DEC_BLOCK / 64; ++w) s += redl[w];
        lp_partials[blockIdx.x] = s;
    }
}

// ---------------------------------------------------------------------------
// Kernel 4: reduce per-block logp partials -> mean -> last element of d_out
// ---------------------------------------------------------------------------
__global__ __launch_bounds__(256) void fin_kernel(
    const float* __restrict__ lp_partials, int nparts, int n_tgt,
    float* __restrict__ out)
{
    __shared__ float red[256];
    float s = 0.f;
    for (int i = threadIdx.x; i < nparts; i += 256) s += lp_partials[i];
    red[threadIdx.x] = s;
    __syncthreads();
    for (int o = 128; o > 0; o >>= 1) {
        if (threadIdx.x < o) red[threadIdx.x] += red[threadIdx.x + o];
        __syncthreads();
    }
    if (threadIdx.x == 0) out[0] = red[0] / (float)n_tgt;
}

extern "C" void kernel_launch(void* const* d_in, const int* in_sizes, int n_in,
                              void* d_out, int out_size, void* d_ws, size_t ws_size,
                              hipStream_t stream)
{
    const float* O    = (const float*)d_in[0];
    const float* T    = (const float*)d_in[1];
    const float* h_W0 = (const float*)d_in[2];
    const float* h_b0 = (const float*)d_in[3];
    const float* h_W1 = (const float*)d_in[4];
    const float* h_b1 = (const float*)d_in[5];
    const float* h_W2 = (const float*)d_in[6];
    const float* h_b2 = (const float*)d_in[7];
    const float* g_W0 = (const float*)d_in[8];
    const float* g_b0 = (const float*)d_in[9];
    const float* g_W1 = (const float*)d_in[10];
    const float* g_b1 = (const float*)d_in[11];
    const float* g_W2 = (const float*)d_in[12];
    const float* g_b2 = (const float*)d_in[13];
    const float* g_W3 = (const float*)d_in[14];
    const float* g_b3 = (const float*)d_in[15];
    const float* g_W4 = (const float*)d_in[16];
    const float* g_b4 = (const float*)d_in[17];

    int n_ctx = in_sizes[0] / 2;
    int n_tgt = in_sizes[1] / 2;

    int enc_blocks = (n_ctx + ENC_BLOCK * ENC_R - 1) / (ENC_BLOCK * ENC_R);
    int dec_blocks = (n_tgt + DEC_BLOCK * DEC_R - 1) / (DEC_BLOCK * DEC_R);

    float* ws           = (float*)d_ws;
    float* enc_partials = ws;                          // 32 * enc_blocks
    float* rW0          = ws + 32 * enc_blocks;        // 64
    float* lp_partials  = rW0 + 64;                    // dec_blocks

    float* phi = (float*)d_out;                        // 2 * n_tgt
    float* lp  = (float*)d_out + (out_size - 1);       // scalar log_prob

    enc_kernel<<<enc_blocks, ENC_BLOCK, 0, stream>>>(O, n_ctx, h_W0, h_b0,
                                                     h_W1, h_b1, enc_partials);
    mid_kernel<<<1, MID_T, 0, stream>>>(enc_partials, enc_blocks, n_ctx,
                                        h_W2, h_b2, g_W0, g_b0, rW0);
    dec_kernel<<<dec_blocks, DEC_BLOCK, 0, stream>>>(T, n_tgt, rW0,
                                                     g_W0 + 128 * 64,
                                                     g_W1, g_b1, g_W2, g_b2,
                                                     g_W3, g_b3, g_W4, g_b4,
                                                     phi, lp_partials);
    fin_kernel<<<1, 256, 0, stream>>>(lp_partials, dec_blocks, n_tgt, lp);
}